// Round 7
// baseline (2810.366 us; speedup 1.0000x reference)
//
#include <hip/hip_runtime.h>

#define HH 50
#define NGATE 200      // 4*H gate rows
#define NB 4           // batch elements per block -> grid 512 = 2 blocks/CU
#define TT 512
#define NTH 512
#define NTILES 13      // ceil(200/16)
#define A0S 72         // shorts/row: 64 k-slots (54 used: h|x|1) + 8 pad = 144B
#define A1S 136        // shorts/row: 128 k-slots (101 used: h1|hB|1) + 8 pad = 272B
#define GS 20          // g row stride (floats), rows indexed by gate n

typedef __attribute__((ext_vector_type(8))) short short8;
typedef __attribute__((ext_vector_type(4))) float f32x4;

__device__ __forceinline__ unsigned short f2bf(float f) {
    unsigned int u = __float_as_uint(f);
    u += 0x7FFFu + ((u >> 16) & 1u);
    return (unsigned short)(u >> 16);
}
__device__ __forceinline__ float bf2f(unsigned short s) {
    return __uint_as_float(((unsigned int)s) << 16);
}
__device__ __forceinline__ float fast_sigmoid(float v) {
    v = fminf(fmaxf(v, -30.f), 30.f);
    return 1.f / (1.f + __expf(-v));
}
__device__ __forceinline__ float fast_tanh(float v) {
    v = fminf(fmaxf(v, -15.f), 15.f);
    float e = __expf(2.f * v);
    return (e - 1.f) / (e + 1.f);
}
__device__ __forceinline__ float cell_h(float pi, float pf, float pg, float po, float& c) {
    float ii = fast_sigmoid(pi), ff = fast_sigmoid(pf);
    float gg = fast_tanh(pg),    oo = fast_sigmoid(po);
    c = ff * c + ii * gg;
    return oo * fast_tanh(c);
}

// Round-7 change vs round-4/6 (1025us plateau): NB 8->4, grid 256->512 so TWO
// blocks are co-resident per CU (launch_bounds 512,4). The 4-barrier-per-step
// pipeline is latency/stall-bound at 1 block/CU (4800 cyc/step vs ~2000 of
// issue work); a second independent block fills the barrier-drain and
// LDS-latency shadows. Round-6 lesson: the register-pin was a no-op (identical
// counters) -- stop fighting remat, attack occupancy.
__global__ __launch_bounds__(NTH, 4) void lstm_mfma_v5(
    const float* __restrict__ x,
    const float* __restrict__ W_ih0, const float* __restrict__ W_hh0,
    const float* __restrict__ b_ih0, const float* __restrict__ b_hh0,
    const float* __restrict__ W_ih1, const float* __restrict__ W_hh1,
    const float* __restrict__ b_ih1, const float* __restrict__ b_hh1,
    const float* __restrict__ fc_w, const float* __restrict__ fc_b,
    float* __restrict__ out)
{
    // A matrices hold bf16-split activations; K includes x and a constant-1
    // bias column so the MFMA produces the COMPLETE gate preactivation.
    __shared__ unsigned short A0hi[16 * A0S], A0lo[16 * A0S];
    __shared__ unsigned short A1hi[16 * A1S], A1lo[16 * A1S];
    __shared__ float g[208 * GS];      // gate preacts, [n][batch]
    __shared__ float hBf[NB * 52];     // final-step hB (fp32) for the FC

    const int tid = threadIdx.x;
    const int n16 = tid & 15;          // MFMA 16-lane index
    const int q4  = (tid >> 4) & 3;    // MFMA quad
    const int wid = tid >> 6;          // wave 0..7, owns N-tiles {wid, wid+8}
    const int b0  = blockIdx.x * NB;

    // ---- zero A state (rows 4..15 and k-pad stay zero forever) ----
    for (int i = tid; i < 16 * A0S; i += NTH) { A0hi[i] = 0; A0lo[i] = 0; }
    for (int i = tid; i < 16 * A1S; i += NTH) { A1hi[i] = 0; A1lo[i] = 0; }
    __syncthreads();

    // ---- constant-1 bias columns (batches 0..NB-1 only) ----
    if (tid < NB) {
        A0hi[tid * A0S + 53]  = 0x3F80;   // bf16 1.0
        A1hi[tid * A1S + 100] = 0x3F80;
    }

    // ---- B-fragments: direct global gather into registers (prologue only) ----
    short8 b0h[2][2], b0l[2][2], b1h[2][4], b1l[2][4];
    #pragma unroll
    for (int ti = 0; ti < 2; ++ti) {
        const int nt = wid + ti * 8;
        const int n = nt * 16 + n16;
        const bool nv = (nt < NTILES) && (n < NGATE);
        #pragma unroll
        for (int kt = 0; kt < 2; ++kt) {     // layer0: K = [Whh0(50)|Wih0(3)|bias]
            short8 hi, lo;
            #pragma unroll
            for (int jj = 0; jj < 8; ++jj) {
                int k = kt * 32 + q4 * 8 + jj;
                float w = 0.f;
                if (nv) {
                    if (k < 50)      w = W_hh0[n * 50 + k];
                    else if (k < 53) w = W_ih0[n * 3 + (k - 50)];
                    else if (k == 53) w = b_ih0[n] + b_hh0[n];
                }
                unsigned short h = f2bf(w);
                hi[jj] = (short)h;
                lo[jj] = (short)f2bf(w - bf2f(h));
            }
            b0h[ti][kt] = hi; b0l[ti][kt] = lo;
        }
        #pragma unroll
        for (int kt = 0; kt < 4; ++kt) {     // layer1: K = [Wih1(50)|Whh1(50)|bias]
            short8 hi, lo;
            #pragma unroll
            for (int jj = 0; jj < 8; ++jj) {
                int k = kt * 32 + q4 * 8 + jj;
                float w = 0.f;
                if (nv) {
                    if (k < 50)       w = W_ih1[n * 50 + k];
                    else if (k < 100) w = W_hh1[n * 50 + (k - 50)];
                    else if (k == 100) w = b_ih1[n] + b_hh1[n];
                }
                unsigned short h = f2bf(w);
                hi[jj] = (short)h;
                lo[jj] = (short)f2bf(w - bf2f(h));
            }
            b1h[ti][kt] = hi; b1l[ti][kt] = lo;
        }
    }

    // ---- cell role: (batch, unit-pair) -> all LDS writes are b32 ----
    const int cb  = tid & 3;           // batch 0..3 (tid < 100 active)
    const int up  = tid >> 2;          // unit pair 0..24
    const int cu0 = 2 * up, cu1 = 2 * up + 1;
    const bool cellAct = (tid < 100);
    float c0a = 0.f, c0b = 0.f, cBa = 0.f, cBb = 0.f;

    // ---- x-writer role: threads 448..459 own (batch, component) ----
    float xv = 0.f;
    size_t xbase = 0;
    int xb = 0, xc = 0;
    if (tid >= 448 && tid < 448 + NB * 3) {
        int i = tid - 448;
        xb = i / 3; xc = i - xb * 3;
        xbase = (size_t)(b0 + xb) * (TT * 3);
        float x0 = x[xbase + xc];                    // t = 0
        unsigned short h = f2bf(x0);
        A0hi[xb * A0S + 50 + xc] = h;
        A0lo[xb * A0S + 50 + xc] = f2bf(x0 - bf2f(h));
        xv = x[xbase + 3 + xc];                      // prefetch t = 1
    }
    __syncthreads();

    for (int t = 0; t < TT; ++t) {
        // ======== P1: layer0 MFMA (full preact incl. x + bias) ========
        {
            short8 a0h_[2], a0l_[2];
            #pragma unroll
            for (int kt = 0; kt < 2; ++kt) {
                a0h_[kt] = *(const short8*)&A0hi[n16 * A0S + kt * 32 + q4 * 8];
                a0l_[kt] = *(const short8*)&A0lo[n16 * A0S + kt * 32 + q4 * 8];
            }
            #pragma unroll
            for (int ti = 0; ti < 2; ++ti) {
                int nt = wid + ti * 8;
                if (nt < NTILES) {
                    f32x4 aa = {0.f,0.f,0.f,0.f}, ab = {0.f,0.f,0.f,0.f};
                    aa = __builtin_amdgcn_mfma_f32_16x16x32_bf16(a0h_[0], b0h[ti][0], aa, 0, 0, 0);
                    aa = __builtin_amdgcn_mfma_f32_16x16x32_bf16(a0l_[0], b0h[ti][0], aa, 0, 0, 0);
                    aa = __builtin_amdgcn_mfma_f32_16x16x32_bf16(a0h_[0], b0l[ti][0], aa, 0, 0, 0);
                    ab = __builtin_amdgcn_mfma_f32_16x16x32_bf16(a0h_[1], b0h[ti][1], ab, 0, 0, 0);
                    ab = __builtin_amdgcn_mfma_f32_16x16x32_bf16(a0l_[1], b0h[ti][1], ab, 0, 0, 0);
                    ab = __builtin_amdgcn_mfma_f32_16x16x32_bf16(a0h_[1], b0l[ti][1], ab, 0, 0, 0);
                    if (q4 == 0)   // only batches 0..3 carry data
                        *(f32x4*)&g[(nt * 16 + n16) * GS] = aa + ab;
                }
            }
        }
        __syncthreads();

        // ======== P2: layer0 cell (pure g->act->h) + x staging ========
        if (cellAct) {
            float h0 = cell_h(g[cu0 * GS + cb],        g[(cu0 + 50) * GS + cb],
                              g[(cu0 + 100) * GS + cb], g[(cu0 + 150) * GS + cb], c0a);
            float h1 = cell_h(g[cu1 * GS + cb],        g[(cu1 + 50) * GS + cb],
                              g[(cu1 + 100) * GS + cb], g[(cu1 + 150) * GS + cb], c0b);
            unsigned short h0h = f2bf(h0), h1h = f2bf(h1);
            unsigned int vhi = (unsigned int)h0h | ((unsigned int)h1h << 16);
            unsigned int vlo = (unsigned int)f2bf(h0 - bf2f(h0h))
                             | ((unsigned int)f2bf(h1 - bf2f(h1h)) << 16);
            *(unsigned int*)&A0hi[cb * A0S + cu0] = vhi;   // layer0 recurrent input
            *(unsigned int*)&A0lo[cb * A0S + cu0] = vlo;
            *(unsigned int*)&A1hi[cb * A1S + cu0] = vhi;   // layer1 input this step
            *(unsigned int*)&A1lo[cb * A1S + cu0] = vlo;
        } else if (tid >= 448 && tid < 448 + NB * 3) {
            unsigned short h = f2bf(xv);                   // x(t+1)
            A0hi[xb * A0S + 50 + xc] = h;
            A0lo[xb * A0S + 50 + xc] = f2bf(xv - bf2f(h));
            int tn = (t + 2 < TT) ? (t + 2) : (TT - 1);
            xv = x[xbase + tn * 3 + xc];
        }
        __syncthreads();

        // ======== P3: layer1 MFMA ========
        {
            short8 a1h_[4], a1l_[4];
            #pragma unroll
            for (int kt = 0; kt < 4; ++kt) {
                a1h_[kt] = *(const short8*)&A1hi[n16 * A1S + kt * 32 + q4 * 8];
                a1l_[kt] = *(const short8*)&A1lo[n16 * A1S + kt * 32 + q4 * 8];
            }
            #pragma unroll
            for (int ti = 0; ti < 2; ++ti) {
                int nt = wid + ti * 8;
                if (nt < NTILES) {
                    f32x4 aa = {0.f,0.f,0.f,0.f}, ab = {0.f,0.f,0.f,0.f};
                    #pragma unroll
                    for (int kt = 0; kt < 2; ++kt) {
                        aa = __builtin_amdgcn_mfma_f32_16x16x32_bf16(a1h_[kt], b1h[ti][kt], aa, 0, 0, 0);
                        aa = __builtin_amdgcn_mfma_f32_16x16x32_bf16(a1l_[kt], b1h[ti][kt], aa, 0, 0, 0);
                        aa = __builtin_amdgcn_mfma_f32_16x16x32_bf16(a1h_[kt], b1l[ti][kt], aa, 0, 0, 0);
                    }
                    #pragma unroll
                    for (int kt = 2; kt < 4; ++kt) {
                        ab = __builtin_amdgcn_mfma_f32_16x16x32_bf16(a1h_[kt], b1h[ti][kt], ab, 0, 0, 0);
                        ab = __builtin_amdgcn_mfma_f32_16x16x32_bf16(a1l_[kt], b1h[ti][kt], ab, 0, 0, 0);
                        ab = __builtin_amdgcn_mfma_f32_16x16x32_bf16(a1h_[kt], b1l[ti][kt], ab, 0, 0, 0);
                    }
                    if (q4 == 0)
                        *(f32x4*)&g[(nt * 16 + n16) * GS] = aa + ab;
                }
            }
        }
        __syncthreads();

        // ======== P4: layer1 cell ========
        if (cellAct) {
            float h0 = cell_h(g[cu0 * GS + cb],        g[(cu0 + 50) * GS + cb],
                              g[(cu0 + 100) * GS + cb], g[(cu0 + 150) * GS + cb], cBa);
            float h1 = cell_h(g[cu1 * GS + cb],        g[(cu1 + 50) * GS + cb],
                              g[(cu1 + 100) * GS + cb], g[(cu1 + 150) * GS + cb], cBb);
            unsigned short h0h = f2bf(h0), h1h = f2bf(h1);
            unsigned int vhi = (unsigned int)h0h | ((unsigned int)h1h << 16);
            unsigned int vlo = (unsigned int)f2bf(h0 - bf2f(h0h))
                             | ((unsigned int)f2bf(h1 - bf2f(h1h)) << 16);
            *(unsigned int*)&A1hi[cb * A1S + 50 + cu0] = vhi;  // next-step hB
            *(unsigned int*)&A1lo[cb * A1S + 50 + cu0] = vlo;
            if (t == TT - 1) {
                hBf[cb * 52 + cu0] = h0;
                hBf[cb * 52 + cu1] = h1;
            }
        }
        __syncthreads();
    }

    // ======== final FC ========
    if (tid < NB * 3) {
        int bb = tid / 3, o = tid - bb * 3;
        float a = fc_b[o];
        #pragma unroll
        for (int uu = 0; uu < HH; ++uu)
            a += hBf[bb * 52 + uu] * fc_w[o * HH + uu];
        out[(size_t)(b0 + bb) * 3 + o] = a;
    }
}

extern "C" void kernel_launch(void* const* d_in, const int* in_sizes, int n_in,
                              void* d_out, int out_size, void* d_ws, size_t ws_size,
                              hipStream_t stream) {
    const float* x     = (const float*)d_in[0];
    const float* W_ih0 = (const float*)d_in[1];
    const float* W_hh0 = (const float*)d_in[2];
    const float* b_ih0 = (const float*)d_in[3];
    const float* b_hh0 = (const float*)d_in[4];
    const float* W_ih1 = (const float*)d_in[5];
    const float* W_hh1 = (const float*)d_in[6];
    const float* b_ih1 = (const float*)d_in[7];
    const float* b_hh1 = (const float*)d_in[8];
    const float* fc_w  = (const float*)d_in[9];
    const float* fc_b  = (const float*)d_in[10];
    float* out = (float*)d_out;

    const int B = 2048;
    dim3 grid(B / NB), block(NTH);
    lstm_mfma_v5<<<grid, block, 0, stream>>>(
        x, W_ih0, W_hh0, b_ih0, b_hh0, W_ih1, W_hh1, b_ih1, b_hh1, fc_w, fc_b, out);
}

// Round 8
// 1012.915 us; speedup vs baseline: 2.7745x; 2.7745x over previous
//
#include <hip/hip_runtime.h>

#define HH 50
#define NGATE 200      // 4*H gate rows
#define NB 8           // batch elements per block
#define TT 512
#define NTH 512
#define NTILES 13      // ceil(200/16)
#define A0S 72         // shorts/row: 64 k-slots (54 used: h|x|1) + 8 pad = 144B
#define A1S 136        // shorts/row: 128 k-slots (101 used: h1|hB|1) + 8 pad = 272B
#define GS 20          // g row stride (floats), rows indexed by gate n
#define NFRAG (NTILES * 12)   // 12 fragment slots per N-tile

typedef __attribute__((ext_vector_type(8))) short short8;
typedef __attribute__((ext_vector_type(4))) float f32x4;

__device__ __forceinline__ unsigned short f2bf(float f) {
    unsigned int u = __float_as_uint(f);
    u += 0x7FFFu + ((u >> 16) & 1u);
    return (unsigned short)(u >> 16);
}
__device__ __forceinline__ float bf2f(unsigned short s) {
    return __uint_as_float(((unsigned int)s) << 16);
}
__device__ __forceinline__ float fast_sigmoid(float v) {
    v = fminf(fmaxf(v, -30.f), 30.f);
    return 1.f / (1.f + __expf(-v));
}
__device__ __forceinline__ float fast_tanh(float v) {
    v = fminf(fmaxf(v, -15.f), 15.f);
    float e = __expf(2.f * v);
    return (e - 1.f) / (e + 1.f);
}
__device__ __forceinline__ float cell_h(float pi, float pf, float pg, float po, float& c) {
    float ii = fast_sigmoid(pi), ff = fast_sigmoid(pf);
    float gg = fast_tanh(pg),    oo = fast_sigmoid(po);
    c = ff * c + ii * gg;
    return oo * fast_tanh(c);
}

// ---------------- prep kernel: build split-bf16 B-fragments in d_ws ----------------
// Fragment slot map per N-tile nt (12 slots):
//   slot 0..3  : layer0 kt{0,1} x {hi,lo}   (K = [Whh0(50)|Wih0(3)|bias1])
//   slot 4..11 : layer1 kt{0..3} x {hi,lo}  (K = [Wih1(50)|Whh1(50)|bias1])
// Storage: ws[( (nt*12+slot)*64 + lane ) * 8 shorts] -- exact per-lane MFMA
// fragment order, so the main kernel's "gather" is ONE coalesced dwordx4 load
// (rounds 4-7 lesson: the compiler re-runs any VALU gather/convert chain every
// timestep; make the rematerializable form a bare load instead of ~40 VALU ops).
__global__ void prep_frags(
    const float* __restrict__ W_ih0, const float* __restrict__ W_hh0,
    const float* __restrict__ b_ih0, const float* __restrict__ b_hh0,
    const float* __restrict__ W_ih1, const float* __restrict__ W_hh1,
    const float* __restrict__ b_ih1, const float* __restrict__ b_hh1,
    unsigned short* __restrict__ ws)
{
    int idx = blockIdx.x * blockDim.x + threadIdx.x;
    if (idx >= NFRAG * 64) return;
    const int lane = idx & 63;
    const int fid  = idx >> 6;
    const int nt   = fid / 12;
    const int slot = fid - nt * 12;
    const int n    = nt * 16 + (lane & 15);
    const int q4   = lane >> 4;
    const int layer = (slot < 4) ? 0 : 1;
    const int s     = (slot < 4) ? slot : (slot - 4);
    const int kt    = s >> 1;
    const int ishi  = !(s & 1);

    short8 v;
    #pragma unroll
    for (int jj = 0; jj < 8; ++jj) {
        int k = kt * 32 + q4 * 8 + jj;
        float w = 0.f;
        if (n < NGATE) {
            if (layer == 0) {
                if (k < 50)       w = W_hh0[n * 50 + k];
                else if (k < 53)  w = W_ih0[n * 3 + (k - 50)];
                else if (k == 53) w = b_ih0[n] + b_hh0[n];
            } else {
                if (k < 50)        w = W_ih1[n * 50 + k];
                else if (k < 100)  w = W_hh1[n * 50 + (k - 50)];
                else if (k == 100) w = b_ih1[n] + b_hh1[n];
            }
        }
        unsigned short h = f2bf(w);
        v[jj] = (short)(ishi ? h : f2bf(w - bf2f(h)));
    }
    *(short8*)&ws[((size_t)fid * 64 + lane) * 8] = v;
}

// ---------------- main kernel: round-6 structure, B-frags from ws ----------------
__global__ __launch_bounds__(NTH, 2) void lstm_mfma_v6(
    const float* __restrict__ x,
    const unsigned short* __restrict__ ws,
    const float* __restrict__ fc_w, const float* __restrict__ fc_b,
    float* __restrict__ out)
{
    __shared__ unsigned short A0hi[16 * A0S], A0lo[16 * A0S];
    __shared__ unsigned short A1hi[16 * A1S], A1lo[16 * A1S];
    __shared__ float g[208 * GS];      // gate preacts, [n][batch]
    __shared__ float hBf[NB * 52];     // final-step hB (fp32) for the FC

    const int tid = threadIdx.x;
    const int n16 = tid & 15;
    const int q4  = (tid >> 4) & 3;
    const int wid = tid >> 6;          // wave 0..7, owns N-tiles {wid, wid+8}
    const int lane = tid & 63;
    const int b0  = blockIdx.x * NB;

    // ---- zero A state (rows 8..15 and k-pad stay zero forever) ----
    for (int i = tid; i < 16 * A0S; i += NTH) { A0hi[i] = 0; A0lo[i] = 0; }
    for (int i = tid; i < 16 * A1S; i += NTH) { A1hi[i] = 0; A1lo[i] = 0; }
    __syncthreads();

    if (tid < NB) {
        A0hi[tid * A0S + 53]  = 0x3F80;   // bf16 1.0 (bias column)
        A1hi[tid * A1S + 100] = 0x3F80;
    }

    // ---- B-fragments: coalesced loads from ws (hoisted or cheaply remat) ----
    const short8* wsf = (const short8*)ws;
    short8 b0h[2][2], b0l[2][2], b1h[2][4], b1l[2][4];
    #pragma unroll
    for (int ti = 0; ti < 2; ++ti) {
        const int nt = wid + ti * 8;
        const bool nv = (nt < NTILES);
        const size_t gbase = (size_t)(nv ? nt : 0) * 12 * 64 + lane;
        #pragma unroll
        for (int kt = 0; kt < 2; ++kt) {
            b0h[ti][kt] = nv ? wsf[gbase + (size_t)(kt * 2 + 0) * 64] : short8{};
            b0l[ti][kt] = nv ? wsf[gbase + (size_t)(kt * 2 + 1) * 64] : short8{};
        }
        #pragma unroll
        for (int kt = 0; kt < 4; ++kt) {
            b1h[ti][kt] = nv ? wsf[gbase + (size_t)(4 + kt * 2 + 0) * 64] : short8{};
            b1l[ti][kt] = nv ? wsf[gbase + (size_t)(4 + kt * 2 + 1) * 64] : short8{};
        }
    }

    // ---- cell role: PAIR of adjacent hidden units -> all LDS writes are b32 ----
    const int cb  = tid & 7;           // batch (tid < 200)
    const int up  = tid >> 3;          // unit pair 0..24
    const int cu0 = 2 * up, cu1 = 2 * up + 1;
    float c0a = 0.f, c0b = 0.f, cBa = 0.f, cBb = 0.f;

    // ---- x-writer role: threads 448..471 own (batch, component) ----
    float xv = 0.f;
    size_t xbase = 0;
    int xb = 0, xc = 0;
    if (tid >= 448 && tid < 448 + NB * 3) {
        int i = tid - 448;
        xb = i / 3; xc = i - xb * 3;
        xbase = (size_t)(b0 + xb) * (TT * 3);
        float x0 = x[xbase + xc];                    // t = 0
        unsigned short h = f2bf(x0);
        A0hi[xb * A0S + 50 + xc] = h;
        A0lo[xb * A0S + 50 + xc] = f2bf(x0 - bf2f(h));
        xv = x[xbase + 3 + xc];                      // prefetch t = 1
    }
    __syncthreads();

    for (int t = 0; t < TT; ++t) {
        // ======== P1: layer0 MFMA (full preact incl. x + bias) ========
        {
            short8 a0h_[2], a0l_[2];
            #pragma unroll
            for (int kt = 0; kt < 2; ++kt) {
                a0h_[kt] = *(const short8*)&A0hi[n16 * A0S + kt * 32 + q4 * 8];
                a0l_[kt] = *(const short8*)&A0lo[n16 * A0S + kt * 32 + q4 * 8];
            }
            #pragma unroll
            for (int ti = 0; ti < 2; ++ti) {
                int nt = wid + ti * 8;
                if (nt < NTILES) {
                    f32x4 aa = {0.f,0.f,0.f,0.f}, ab = {0.f,0.f,0.f,0.f};
                    aa = __builtin_amdgcn_mfma_f32_16x16x32_bf16(a0h_[0], b0h[ti][0], aa, 0, 0, 0);
                    aa = __builtin_amdgcn_mfma_f32_16x16x32_bf16(a0l_[0], b0h[ti][0], aa, 0, 0, 0);
                    aa = __builtin_amdgcn_mfma_f32_16x16x32_bf16(a0h_[0], b0l[ti][0], aa, 0, 0, 0);
                    ab = __builtin_amdgcn_mfma_f32_16x16x32_bf16(a0h_[1], b0h[ti][1], ab, 0, 0, 0);
                    ab = __builtin_amdgcn_mfma_f32_16x16x32_bf16(a0l_[1], b0h[ti][1], ab, 0, 0, 0);
                    ab = __builtin_amdgcn_mfma_f32_16x16x32_bf16(a0h_[1], b0l[ti][1], ab, 0, 0, 0);
                    if (q4 < 2)   // only batches 0..7 carry data
                        *(f32x4*)&g[(nt * 16 + n16) * GS + q4 * 4] = aa + ab;
                }
            }
        }
        __syncthreads();

        // ======== P2: layer0 cell (pure g->act->h) + x staging ========
        if (tid < 200) {
            float h0 = cell_h(g[cu0 * GS + cb],        g[(cu0 + 50) * GS + cb],
                              g[(cu0 + 100) * GS + cb], g[(cu0 + 150) * GS + cb], c0a);
            float h1 = cell_h(g[cu1 * GS + cb],        g[(cu1 + 50) * GS + cb],
                              g[(cu1 + 100) * GS + cb], g[(cu1 + 150) * GS + cb], c0b);
            unsigned short h0h = f2bf(h0), h1h = f2bf(h1);
            unsigned int vhi = (unsigned int)h0h | ((unsigned int)h1h << 16);
            unsigned int vlo = (unsigned int)f2bf(h0 - bf2f(h0h))
                             | ((unsigned int)f2bf(h1 - bf2f(h1h)) << 16);
            *(unsigned int*)&A0hi[cb * A0S + cu0] = vhi;   // layer0 recurrent input
            *(unsigned int*)&A0lo[cb * A0S + cu0] = vlo;
            *(unsigned int*)&A1hi[cb * A1S + cu0] = vhi;   // layer1 input this step
            *(unsigned int*)&A1lo[cb * A1S + cu0] = vlo;
        } else if (tid >= 448 && tid < 448 + NB * 3) {
            unsigned short h = f2bf(xv);                   // x(t+1)
            A0hi[xb * A0S + 50 + xc] = h;
            A0lo[xb * A0S + 50 + xc] = f2bf(xv - bf2f(h));
            int tn = (t + 2 < TT) ? (t + 2) : (TT - 1);
            xv = x[xbase + tn * 3 + xc];
        }
        __syncthreads();

        // ======== P3: layer1 MFMA ========
        {
            short8 a1h_[4], a1l_[4];
            #pragma unroll
            for (int kt = 0; kt < 4; ++kt) {
                a1h_[kt] = *(const short8*)&A1hi[n16 * A1S + kt * 32 + q4 * 8];
                a1l_[kt] = *(const short8*)&A1lo[n16 * A1S + kt * 32 + q4 * 8];
            }
            #pragma unroll
            for (int ti = 0; ti < 2; ++ti) {
                int nt = wid + ti * 8;
                if (nt < NTILES) {
                    f32x4 aa = {0.f,0.f,0.f,0.f}, ab = {0.f,0.f,0.f,0.f};
                    #pragma unroll
                    for (int kt = 0; kt < 2; ++kt) {
                        aa = __builtin_amdgcn_mfma_f32_16x16x32_bf16(a1h_[kt], b1h[ti][kt], aa, 0, 0, 0);
                        aa = __builtin_amdgcn_mfma_f32_16x16x32_bf16(a1l_[kt], b1h[ti][kt], aa, 0, 0, 0);
                        aa = __builtin_amdgcn_mfma_f32_16x16x32_bf16(a1h_[kt], b1l[ti][kt], aa, 0, 0, 0);
                    }
                    #pragma unroll
                    for (int kt = 2; kt < 4; ++kt) {
                        ab = __builtin_amdgcn_mfma_f32_16x16x32_bf16(a1h_[kt], b1h[ti][kt], ab, 0, 0, 0);
                        ab = __builtin_amdgcn_mfma_f32_16x16x32_bf16(a1l_[kt], b1h[ti][kt], ab, 0, 0, 0);
                        ab = __builtin_amdgcn_mfma_f32_16x16x32_bf16(a1h_[kt], b1l[ti][kt], ab, 0, 0, 0);
                    }
                    if (q4 < 2)
                        *(f32x4*)&g[(nt * 16 + n16) * GS + q4 * 4] = aa + ab;
                }
            }
        }
        __syncthreads();

        // ======== P4: layer1 cell ========
        if (tid < 200) {
            float h0 = cell_h(g[cu0 * GS + cb],        g[(cu0 + 50) * GS + cb],
                              g[(cu0 + 100) * GS + cb], g[(cu0 + 150) * GS + cb], cBa);
            float h1 = cell_h(g[cu1 * GS + cb],        g[(cu1 + 50) * GS + cb],
                              g[(cu1 + 100) * GS + cb], g[(cu1 + 150) * GS + cb], cBb);
            unsigned short h0h = f2bf(h0), h1h = f2bf(h1);
            unsigned int vhi = (unsigned int)h0h | ((unsigned int)h1h << 16);
            unsigned int vlo = (unsigned int)f2bf(h0 - bf2f(h0h))
                             | ((unsigned int)f2bf(h1 - bf2f(h1h)) << 16);
            *(unsigned int*)&A1hi[cb * A1S + 50 + cu0] = vhi;  // next-step hB
            *(unsigned int*)&A1lo[cb * A1S + 50 + cu0] = vlo;
            if (t == TT - 1) {
                hBf[cb * 52 + cu0] = h0;
                hBf[cb * 52 + cu1] = h1;
            }
        }
        __syncthreads();
    }

    // ======== final FC ========
    if (tid < NB * 3) {
        int bb = tid / 3, o = tid - bb * 3;
        float a = fc_b[o];
        #pragma unroll
        for (int uu = 0; uu < HH; ++uu)
            a += hBf[bb * 52 + uu] * fc_w[o * HH + uu];
        out[(size_t)(b0 + bb) * 3 + o] = a;
    }
}

extern "C" void kernel_launch(void* const* d_in, const int* in_sizes, int n_in,
                              void* d_out, int out_size, void* d_ws, size_t ws_size,
                              hipStream_t stream) {
    const float* x     = (const float*)d_in[0];
    const float* W_ih0 = (const float*)d_in[1];
    const float* W_hh0 = (const float*)d_in[2];
    const float* b_ih0 = (const float*)d_in[3];
    const float* b_hh0 = (const float*)d_in[4];
    const float* W_ih1 = (const float*)d_in[5];
    const float* W_hh1 = (const float*)d_in[6];
    const float* b_ih1 = (const float*)d_in[7];
    const float* b_hh1 = (const float*)d_in[8];
    const float* fc_w  = (const float*)d_in[9];
    const float* fc_b  = (const float*)d_in[10];
    float* out = (float*)d_out;
    unsigned short* ws = (unsigned short*)d_ws;   // needs NFRAG*64*16 B = 156 KB

    const int prepN = NFRAG * 64;
    prep_frags<<<(prepN + 255) / 256, 256, 0, stream>>>(
        W_ih0, W_hh0, b_ih0, b_hh0, W_ih1, W_hh1, b_ih1, b_hh1, ws);

    const int B = 2048;
    dim3 grid(B / NB), block(NTH);
    lstm_mfma_v6<<<grid, block, 0, stream>>>(x, ws, fc_w, fc_b, out);
}

// Round 9
// 881.369 us; speedup vs baseline: 3.1886x; 1.1493x over previous
//
#include <hip/hip_runtime.h>

#define HH 50
#define NGATE 200      // 4*H gate rows
#define NB 8           // batch elements per block
#define TT 512
#define NTH 512
#define NTILES 13      // ceil(200/16)
#define A0S 72         // shorts/row: 64 k-slots (54 used: h|x|1) + 8 pad = 144B
#define A1S 136        // shorts/row: 128 k-slots (101 used: h1|hB|1) + 8 pad = 272B
#define GS 20          // g row stride (floats), rows indexed by gate n
#define NFRAG (NTILES * 12)   // 12 fragment slots per N-tile

typedef __attribute__((ext_vector_type(8))) short short8;
typedef __attribute__((ext_vector_type(4))) float f32x4;

__device__ __forceinline__ unsigned short f2bf(float f) {
    unsigned int u = __float_as_uint(f);
    u += 0x7FFFu + ((u >> 16) & 1u);
    return (unsigned short)(u >> 16);
}
__device__ __forceinline__ float bf2f(unsigned short s) {
    return __uint_as_float(((unsigned int)s) << 16);
}
__device__ __forceinline__ float fast_sigmoid(float v) {
    v = fminf(fmaxf(v, -30.f), 30.f);
    return 1.f / (1.f + __expf(-v));
}
__device__ __forceinline__ float fast_tanh(float v) {
    v = fminf(fmaxf(v, -15.f), 15.f);
    float e = __expf(2.f * v);
    return (e - 1.f) / (e + 1.f);
}
__device__ __forceinline__ float cell_h(float pi, float pf, float pg, float po, float& c) {
    float ii = fast_sigmoid(pi), ff = fast_sigmoid(pf);
    float gg = fast_tanh(pg),    oo = fast_sigmoid(po);
    c = ff * c + ii * gg;
    return oo * fast_tanh(c);
}

// ---------------- prep kernel: build split-bf16 B-fragments in d_ws ----------------
// (unchanged from round 8; slot map per N-tile nt:
//   slot 0..3  : layer0 kt{0,1} x {hi,lo}   (K = [Whh0(50)|Wih0(3)|bias1])
//   slot 4..11 : layer1 kt{0..3} x {hi,lo}  (K = [Wih1(50)|Whh1(50)|bias1]) )
__global__ void prep_frags(
    const float* __restrict__ W_ih0, const float* __restrict__ W_hh0,
    const float* __restrict__ b_ih0, const float* __restrict__ b_hh0,
    const float* __restrict__ W_ih1, const float* __restrict__ W_hh1,
    const float* __restrict__ b_ih1, const float* __restrict__ b_hh1,
    unsigned short* __restrict__ ws)
{
    int idx = blockIdx.x * blockDim.x + threadIdx.x;
    if (idx >= NFRAG * 64) return;
    const int lane = idx & 63;
    const int fid  = idx >> 6;
    const int nt   = fid / 12;
    const int slot = fid - nt * 12;
    const int n    = nt * 16 + (lane & 15);
    const int q4   = lane >> 4;
    const int layer = (slot < 4) ? 0 : 1;
    const int s     = (slot < 4) ? slot : (slot - 4);
    const int kt    = s >> 1;
    const int ishi  = !(s & 1);

    short8 v;
    #pragma unroll
    for (int jj = 0; jj < 8; ++jj) {
        int k = kt * 32 + q4 * 8 + jj;
        float w = 0.f;
        if (n < NGATE) {
            if (layer == 0) {
                if (k < 50)       w = W_hh0[n * 50 + k];
                else if (k < 53)  w = W_ih0[n * 3 + (k - 50)];
                else if (k == 53) w = b_ih0[n] + b_hh0[n];
            } else {
                if (k < 50)        w = W_ih1[n * 50 + k];
                else if (k < 100)  w = W_hh1[n * 50 + (k - 50)];
                else if (k == 100) w = b_ih1[n] + b_hh1[n];
            }
        }
        unsigned short h = f2bf(w);
        v[jj] = (short)(ishi ? h : f2bf(w - bf2f(h)));
    }
    *(short8*)&ws[((size_t)fid * 64 + lane) * 8] = v;
}

// ---------------- main kernel: wave-specialized 2-barrier pipeline ----------------
// Rounds 4/6/8 (identical 1013-1025us with 3 different B-frag schemes) prove the
// floor is the 4-phase serial structure, not weight handling. This round: layer0
// MFMA on waves 0-2 (tiles w+3i), layer1 MFMA lagged one step on waves 3-7
// (tiles (w-3)+5i) in ONE phase; both cell updates in ONE phase. 2 barriers/step.
// Unlike round 5 (regressed, conflicts 7x): no staging union, and each wave reads
// only ITS layer's A operands (4 or 8 b128, vs 12 for every wave).
__global__ __launch_bounds__(NTH, 2) void lstm_mfma_v7(
    const float* __restrict__ x,
    const unsigned short* __restrict__ ws,
    const float* __restrict__ fc_w, const float* __restrict__ fc_b,
    float* __restrict__ out)
{
    __shared__ unsigned short A0hi[16 * A0S], A0lo[16 * A0S];
    __shared__ unsigned short A1hi[16 * A1S], A1lo[16 * A1S];
    __shared__ float g0[208 * GS];     // layer0 gate preacts [n][batch]
    __shared__ float g1[208 * GS];     // layer1 gate preacts (one step behind)
    __shared__ float hBf[NB * 52];     // final-step hB (fp32) for the FC

    const int tid = threadIdx.x;
    const int n16 = tid & 15;
    const int q4  = (tid >> 4) & 3;
    const int wid = tid >> 6;
    const int lane = tid & 63;
    const int b0  = blockIdx.x * NB;

    // ---- zero A state ----
    for (int i = tid; i < 16 * A0S; i += NTH) { A0hi[i] = 0; A0lo[i] = 0; }
    for (int i = tid; i < 16 * A1S; i += NTH) { A1hi[i] = 0; A1lo[i] = 0; }
    __syncthreads();

    if (tid < NB) {
        A0hi[tid * A0S + 53]  = 0x3F80;   // bf16 1.0 (bias column)
        A1hi[tid * A1S + 100] = 0x3F80;
    }

    // ---- B-fragments from ws (coalesced; residency proven irrelevant) ----
    const short8* wsf = (const short8*)ws;
    short8 f0h[5][2], f0l[5][2];       // layer0 waves: tiles wid + 3*i
    short8 f1h[3][4], f1l[3][4];       // layer1 waves: tiles (wid-3) + 5*i
    if (wid < 3) {
        #pragma unroll
        for (int i = 0; i < 5; ++i) {
            const int nt = wid + 3 * i;
            const bool nv = (nt < NTILES);
            const size_t gbase = (size_t)(nv ? nt : 0) * 12 * 64 + lane;
            #pragma unroll
            for (int kt = 0; kt < 2; ++kt) {
                f0h[i][kt] = nv ? wsf[gbase + (size_t)(kt * 2 + 0) * 64] : short8{};
                f0l[i][kt] = nv ? wsf[gbase + (size_t)(kt * 2 + 1) * 64] : short8{};
            }
        }
    } else {
        #pragma unroll
        for (int i = 0; i < 3; ++i) {
            const int nt = (wid - 3) + 5 * i;
            const bool nv = (nt < NTILES);
            const size_t gbase = (size_t)(nv ? nt : 0) * 12 * 64 + lane;
            #pragma unroll
            for (int kt = 0; kt < 4; ++kt) {
                f1h[i][kt] = nv ? wsf[gbase + (size_t)(4 + kt * 2 + 0) * 64] : short8{};
                f1l[i][kt] = nv ? wsf[gbase + (size_t)(4 + kt * 2 + 1) * 64] : short8{};
            }
        }
    }

    // ---- cell roles ----
    const int cb0 = tid & 7,  up0 = tid >> 3;          // L0 cells: tid < 200
    const int t2  = tid - 256;
    const int cb1 = t2 & 7,   up1 = t2 >> 3;           // L1 cells: 256 <= tid < 456
    float c0a = 0.f, c0b = 0.f, cBa = 0.f, cBb = 0.f;

    // ---- x-writer role: threads 456..479 ----
    float xv = 0.f;
    size_t xbase = 0;
    int xb = 0, xc = 0;
    if (tid >= 456 && tid < 456 + NB * 3) {
        int i = tid - 456;
        xb = i / 3; xc = i - xb * 3;
        xbase = (size_t)(b0 + xb) * (TT * 3);
        float x0 = x[xbase + xc];                    // t = 0
        unsigned short h = f2bf(x0);
        A0hi[xb * A0S + 50 + xc] = h;
        A0lo[xb * A0S + 50 + xc] = f2bf(x0 - bf2f(h));
        xv = x[xbase + 3 + xc];                      // prefetch t = 1
    }
    __syncthreads();

    // ================= PIPELINED MAIN LOOP (TT+1 iterations) =================
    // iter t: phase M computes g0(t) [waves 0-2, t<TT] and g1(t-1) [waves 3-7, t>0];
    //         phase C computes h0(t) [t<TT] and hB(t-1) [t>0].
    for (int t = 0; t <= TT; ++t) {
        // -------- phase M --------
        if (wid < 3) {
            if (t < TT) {
                short8 a0h_[2], a0l_[2];
                #pragma unroll
                for (int kt = 0; kt < 2; ++kt) {
                    a0h_[kt] = *(const short8*)&A0hi[n16 * A0S + kt * 32 + q4 * 8];
                    a0l_[kt] = *(const short8*)&A0lo[n16 * A0S + kt * 32 + q4 * 8];
                }
                #pragma unroll
                for (int i = 0; i < 5; ++i) {
                    const int nt = wid + 3 * i;
                    if (nt < NTILES) {
                        f32x4 aa = {0.f,0.f,0.f,0.f}, ab = {0.f,0.f,0.f,0.f};
                        aa = __builtin_amdgcn_mfma_f32_16x16x32_bf16(a0h_[0], f0h[i][0], aa, 0, 0, 0);
                        aa = __builtin_amdgcn_mfma_f32_16x16x32_bf16(a0l_[0], f0h[i][0], aa, 0, 0, 0);
                        aa = __builtin_amdgcn_mfma_f32_16x16x32_bf16(a0h_[0], f0l[i][0], aa, 0, 0, 0);
                        ab = __builtin_amdgcn_mfma_f32_16x16x32_bf16(a0h_[1], f0h[i][1], ab, 0, 0, 0);
                        ab = __builtin_amdgcn_mfma_f32_16x16x32_bf16(a0l_[1], f0h[i][1], ab, 0, 0, 0);
                        ab = __builtin_amdgcn_mfma_f32_16x16x32_bf16(a0h_[1], f0l[i][1], ab, 0, 0, 0);
                        if (q4 < 2)
                            *(f32x4*)&g0[(nt * 16 + n16) * GS + q4 * 4] = aa + ab;
                    }
                }
            }
        } else {
            if (t > 0) {
                short8 a1h_[4], a1l_[4];
                #pragma unroll
                for (int kt = 0; kt < 4; ++kt) {
                    a1h_[kt] = *(const short8*)&A1hi[n16 * A1S + kt * 32 + q4 * 8];
                    a1l_[kt] = *(const short8*)&A1lo[n16 * A1S + kt * 32 + q4 * 8];
                }
                #pragma unroll
                for (int i = 0; i < 3; ++i) {
                    const int nt = (wid - 3) + 5 * i;
                    if (nt < NTILES) {
                        f32x4 aa = {0.f,0.f,0.f,0.f}, ab = {0.f,0.f,0.f,0.f};
                        #pragma unroll
                        for (int kt = 0; kt < 2; ++kt) {
                            aa = __builtin_amdgcn_mfma_f32_16x16x32_bf16(a1h_[kt], f1h[i][kt], aa, 0, 0, 0);
                            aa = __builtin_amdgcn_mfma_f32_16x16x32_bf16(a1l_[kt], f1h[i][kt], aa, 0, 0, 0);
                            aa = __builtin_amdgcn_mfma_f32_16x16x32_bf16(a1h_[kt], f1l[i][kt], aa, 0, 0, 0);
                        }
                        #pragma unroll
                        for (int kt = 2; kt < 4; ++kt) {
                            ab = __builtin_amdgcn_mfma_f32_16x16x32_bf16(a1h_[kt], f1h[i][kt], ab, 0, 0, 0);
                            ab = __builtin_amdgcn_mfma_f32_16x16x32_bf16(a1l_[kt], f1h[i][kt], ab, 0, 0, 0);
                            ab = __builtin_amdgcn_mfma_f32_16x16x32_bf16(a1h_[kt], f1l[i][kt], ab, 0, 0, 0);
                        }
                        if (q4 < 2)
                            *(f32x4*)&g1[(nt * 16 + n16) * GS + q4 * 4] = aa + ab;
                    }
                }
            }
        }
        __syncthreads();

        // -------- phase C --------
        if (tid < 200) {
            if (t < TT) {
                const int cu0 = 2 * up0, cu1 = cu0 + 1;
                float h0 = cell_h(g0[cu0 * GS + cb0],         g0[(cu0 + 50) * GS + cb0],
                                  g0[(cu0 + 100) * GS + cb0], g0[(cu0 + 150) * GS + cb0], c0a);
                float h1 = cell_h(g0[cu1 * GS + cb0],         g0[(cu1 + 50) * GS + cb0],
                                  g0[(cu1 + 100) * GS + cb0], g0[(cu1 + 150) * GS + cb0], c0b);
                unsigned short h0h = f2bf(h0), h1h = f2bf(h1);
                unsigned int vhi = (unsigned int)h0h | ((unsigned int)h1h << 16);
                unsigned int vlo = (unsigned int)f2bf(h0 - bf2f(h0h))
                                 | ((unsigned int)f2bf(h1 - bf2f(h1h)) << 16);
                *(unsigned int*)&A0hi[cb0 * A0S + cu0] = vhi;   // layer0 recurrent input
                *(unsigned int*)&A0lo[cb0 * A0S + cu0] = vlo;
                *(unsigned int*)&A1hi[cb0 * A1S + cu0] = vhi;   // layer1 input (consumed M(t+1))
                *(unsigned int*)&A1lo[cb0 * A1S + cu0] = vlo;
            }
        } else if (tid >= 256 && tid < 456) {
            if (t > 0) {
                const int cu0 = 2 * up1, cu1 = cu0 + 1;
                float h0 = cell_h(g1[cu0 * GS + cb1],         g1[(cu0 + 50) * GS + cb1],
                                  g1[(cu0 + 100) * GS + cb1], g1[(cu0 + 150) * GS + cb1], cBa);
                float h1 = cell_h(g1[cu1 * GS + cb1],         g1[(cu1 + 50) * GS + cb1],
                                  g1[(cu1 + 100) * GS + cb1], g1[(cu1 + 150) * GS + cb1], cBb);
                unsigned short h0h = f2bf(h0), h1h = f2bf(h1);
                unsigned int vhi = (unsigned int)h0h | ((unsigned int)h1h << 16);
                unsigned int vlo = (unsigned int)f2bf(h0 - bf2f(h0h))
                                 | ((unsigned int)f2bf(h1 - bf2f(h1h)) << 16);
                *(unsigned int*)&A1hi[cb1 * A1S + 50 + cu0] = vhi;  // recurrent hB
                *(unsigned int*)&A1lo[cb1 * A1S + 50 + cu0] = vlo;
                if (t == TT) {
                    hBf[cb1 * 52 + cu0] = h0;
                    hBf[cb1 * 52 + cu1] = h1;
                }
            }
        } else if (tid >= 456 && tid < 456 + NB * 3) {
            unsigned short h = f2bf(xv);                   // x(t+1) (clamped at tail; harmless)
            A0hi[xb * A0S + 50 + xc] = h;
            A0lo[xb * A0S + 50 + xc] = f2bf(xv - bf2f(h));
            int tn = (t + 2 < TT) ? (t + 2) : (TT - 1);
            xv = x[xbase + tn * 3 + xc];
        }
        __syncthreads();
    }

    // ======== final FC ========
    if (tid < NB * 3) {
        int bb = tid / 3, o = tid - bb * 3;
        float a = fc_b[o];
        #pragma unroll
        for (int uu = 0; uu < HH; ++uu)
            a += hBf[bb * 52 + uu] * fc_w[o * HH + uu];
        out[(size_t)(b0 + bb) * 3 + o] = a;
    }
}

extern "C" void kernel_launch(void* const* d_in, const int* in_sizes, int n_in,
                              void* d_out, int out_size, void* d_ws, size_t ws_size,
                              hipStream_t stream) {
    const float* x     = (const float*)d_in[0];
    const float* W_ih0 = (const float*)d_in[1];
    const float* W_hh0 = (const float*)d_in[2];
    const float* b_ih0 = (const float*)d_in[3];
    const float* b_hh0 = (const float*)d_in[4];
    const float* W_ih1 = (const float*)d_in[5];
    const float* W_hh1 = (const float*)d_in[6];
    const float* b_ih1 = (const float*)d_in[7];
    const float* b_hh1 = (const float*)d_in[8];
    const float* fc_w  = (const float*)d_in[9];
    const float* fc_b  = (const float*)d_in[10];
    float* out = (float*)d_out;
    unsigned short* ws = (unsigned short*)d_ws;   // needs NFRAG*64*16 B = 156 KB

    const int prepN = NFRAG * 64;
    prep_frags<<<(prepN + 255) / 256, 256, 0, stream>>>(
        W_ih0, W_hh0, b_ih0, b_hh0, W_ih1, W_hh1, b_ih1, b_hh1, ws);

    const int B = 2048;
    dim3 grid(B / NB), block(NTH);
    lstm_mfma_v7<<<grid, block, 0, stream>>>(x, ws, fc_w, fc_b, out);
}